// Round 10
// baseline (732.289 us; speedup 1.0000x reference)
//
#include <hip/hip_runtime.h>

// Problem constants
#define BB   512
#define CC   22
#define TT   1000
#define HH   64
#define NCLS 4
#define FCW  (TT * HH)       // 64000: W_fc row length
#define TBX  100             // t-tile per xproj block (10 tiles/row)
#define TCF  250             // rec: t-chunk for batched FC / h history

typedef _Float16 f16;
typedef __attribute__((ext_vector_type(2))) _Float16 h2;

__device__ __forceinline__ float sigm(float x) {
    float e = __expf(-x);
    return __builtin_amdgcn_rcpf(1.0f + e);
}
__device__ __forceinline__ float tanh_(float x) {
    float e = __expf(-2.0f * fabsf(x));   // (0,1], no overflow
    float r = (1.0f - e) * __builtin_amdgcn_rcpf(1.0f + e);
    return copysignf(r, x);
}
__device__ __forceinline__ h2 u2h(unsigned u) {
    union { unsigned u; h2 h; } c; c.u = u; return c.h;
}
__device__ __forceinline__ unsigned h2u(h2 h) {
    union { unsigned u; h2 h; } c; c.h = h; return c.u;
}
__device__ __forceinline__ unsigned pack2(float a, float b) {
    union { unsigned u; h2 h; } c;
    c.h = h2{(f16)a, (f16)b};
    return c.u;
}

// full-row DPP move: dst[l] = src[sel(l)]
#define DPP(v, ctrl) __builtin_amdgcn_mov_dpp((v), (ctrl), 0xF, 0xF, false)
// dpp_ctrl codes: quad_perm[1,0,3,2]=0xB1 (xor1), quad_perm[2,3,0,1]=0x4E (xor2),
// ROW_HALF_MIRROR=0x141 (xor7), ROW_MIRROR=0x140 (xor15)
// ds_swizzle BitMode xor16: offset = (16<<10)|31 = 0x401F

// butterfly mask for register slot r (bit -> xor mask): must match weight load
__device__ __forceinline__ int slotmask(int r) {
    return ((r & 1) ? 2 : 0) ^ ((r & 2) ? 7 : 0) ^ ((r & 4) ? 15 : 0)
         ^ ((r & 8) ? 16 : 0) ^ ((r & 16) ? 32 : 0);
}

// ---------------------------------------------------------------------------
// R14 kernel 1: x-projection (R13 structure, 2x blocks: TBX 200 -> 100).
// ---------------------------------------------------------------------------
__global__ __launch_bounds__(256) void xproj(
    const float* __restrict__ x,     // [B, C, T]
    const float* __restrict__ W_ih,  // [4H, C]
    const float* __restrict__ b_ih,  // [4H]
    const float* __restrict__ b_hh,  // [4H]
    uint2* __restrict__ xp)          // [B*T*64] uint2
{
    __shared__ __align__(16) h2 xt[TBX][12];   // 4.8 KB

    const int tid = threadIdx.x;
    const int t0  = blockIdx.x * TBX;
    const int b   = blockIdx.y;
    const int hid = tid & 63;
    const int tsub = tid >> 6;       // 4 t-phases

    if (tid < TBX) {
        const float* gx = x + (size_t)b * (CC * TT) + t0 + tid;
        union { h2 h[12]; uint4 q[3]; } U;
        #pragma unroll
        for (int k = 0; k < 11; ++k)
            U.h[k] = h2{(f16)gx[(2 * k) * TT], (f16)gx[(2 * k + 1) * TT]};
        U.h[11] = h2{(f16)0.0f, (f16)0.0f};
        uint4* dst = (uint4*)&xt[tid][0];
        dst[0] = U.q[0]; dst[1] = U.q[1]; dst[2] = U.q[2];
    }

    unsigned wih[4][11];
    float bias[4];
    #pragma unroll
    for (int g = 0; g < 4; ++g) {
        const float* wi = W_ih + (g * HH + hid) * CC;
        #pragma unroll
        for (int k = 0; k < 11; ++k)
            wih[g][k] = h2u(h2{(f16)wi[2 * k], (f16)wi[2 * k + 1]});
        bias[g] = b_ih[g * HH + hid] + b_hh[g * HH + hid];
    }
    __syncthreads();

    uint2* op = xp + ((size_t)b * TT + t0) * 64 + hid;
    for (int t = tsub; t < TBX; t += 4) {
        union { uint4 q[3]; h2 h[12]; } X;
        const uint4* xr = (const uint4*)&xt[t][0];   // broadcast b128
        X.q[0] = xr[0]; X.q[1] = xr[1]; X.q[2] = xr[2];
        float a0 = bias[0], a1 = bias[1], a2 = bias[2], a3 = bias[3];
        #pragma unroll
        for (int k = 0; k < 11; ++k) {
            a0 = __builtin_amdgcn_fdot2(X.h[k], u2h(wih[0][k]), a0, false);
            a1 = __builtin_amdgcn_fdot2(X.h[k], u2h(wih[1][k]), a1, false);
            a2 = __builtin_amdgcn_fdot2(X.h[k], u2h(wih[2][k]), a2, false);
            a3 = __builtin_amdgcn_fdot2(X.h[k], u2h(wih[3][k]), a3, false);
        }
        op[(size_t)t * 64] = uint2{pack2(a0, a1), pack2(a2, a3)};
    }
}

// ---------------------------------------------------------------------------
// R14 kernel 2: single-wave recurrence with REGISTER-RESIDENT h allgather.
// R13 post-mortem: step ~1230 cyc with a ~460-cyc issue model; the remaining
// on-chain latency is the h LDS round-trip (cvt -> ds_write -> 8x ds_read ->
// fdot), ~240-300 cyc/step that no prefetch can hide because h is born at the
// end of the previous step. Replace it with an in-register butterfly:
//   P = pack2(h[l], h[l^1])  (1 DPP + pack)
//   Wr[r] = P from lane l ^ M(r),  M(r) = xor of {2,7,15,16,32} per r bits
// built with 28 DPP moves (VALU, 2cyc) + 2 ds_swizzle(xor16) + 1 shfl_xor(32)
// (only 3 DS-pipe ops). The hid scrambling is folded into the WEIGHT LOAD:
// whh[g][r] holds the pair for hids {l^M(r), l^M(r)^1} -- fdot loop unchanged,
// bit-identical math (f32 accumulation order differs only).
// h still goes to hst (1 ds_write_b16) for the chunk-end batched FC, but
// nothing reads it inside the step -> off the critical path.
// ---------------------------------------------------------------------------
__global__ __attribute__((amdgpu_waves_per_eu(1, 1)))
__launch_bounds__(64) void lstm_rec(
    const uint2* __restrict__ xp,    // [B, T, 64] uint2 (4 f16 gates)
    const float* __restrict__ W_hh,  // [4H, H]
    const float* __restrict__ W_fc,  // [NCLS, T*H]
    const float* __restrict__ b_fc,  // [NCLS]
    float* __restrict__ out)         // [B, NCLS]
{
    __shared__ __align__(16) f16 hst[TCF][HH];   // 32 KB: h history (FC only)

    const int lane = threadIdx.x;    // hidden unit
    const int r    = blockIdx.x;     // batch row

    // per-lane recurrent weights, butterfly-permuted to match Wr slots
    unsigned whh[4][32];
    #pragma unroll
    for (int g = 0; g < 4; ++g) {
        const float* wr = W_hh + (g * HH + lane) * HH;
        #pragma unroll
        for (int k = 0; k < 32; ++k) {
            const int m    = slotmask(k);
            const int hid0 = lane ^ m;        // elem 0 of slot k
            const int hid1 = hid0 ^ 1;        // elem 1
            whh[g][k] = pack2(wr[hid0], wr[hid1]);
        }
    }
    #pragma unroll
    for (int g = 0; g < 4; ++g)
        #pragma unroll
        for (int k = 0; k < 32; ++k) asm volatile("" : "+v"(whh[g][k]));

    float c = 0.0f;
    float fc0 = 0.f, fc1 = 0.f, fc2 = 0.f, fc3 = 0.f;
    const uint2* px = xp + (size_t)r * TT * HH + lane;

    // 3-deep xp pipeline (6 VGPRs)
    uint2 xvA = px[0];
    uint2 xvB = px[HH];
    uint2 xvC = px[2 * HH];

    // h_0 = 0: all gather slots zero
    unsigned Wr[32];
    #pragma unroll
    for (int k = 0; k < 32; ++k) Wr[k] = 0u;

    for (int chunk = 0; chunk < 4; ++chunk) {
        const int T0 = chunk * TCF;

        for (int tt = 0; tt < TCF; ++tt) {
            const int t = T0 + tt;

            // prefetch step t+3 (clamped at tail)
            const int tp = (t + 3 < TT) ? t + 3 : TT - 1;
            const uint2 xvN = px[(size_t)tp * HH];

            // gates: init from the long-arrived xp value, then 128 fdot2
            const h2 pif = u2h(xvA.x), pgo = u2h(xvA.y);
            float a0 = (float)pif[0], a1 = (float)pif[1];
            float a2 = (float)pgo[0], a3 = (float)pgo[1];
            #pragma unroll
            for (int k = 0; k < 32; ++k) {
                a0 = __builtin_amdgcn_fdot2(u2h(Wr[k]), u2h(whh[0][k]), a0, false);
                a1 = __builtin_amdgcn_fdot2(u2h(Wr[k]), u2h(whh[1][k]), a1, false);
                a2 = __builtin_amdgcn_fdot2(u2h(Wr[k]), u2h(whh[2][k]), a2, false);
                a3 = __builtin_amdgcn_fdot2(u2h(Wr[k]), u2h(whh[3][k]), a3, false);
            }

            // lane-local LSTM update
            const float iv = sigm(a0), fv = sigm(a1);
            const float gv = tanh_(a2), ov = sigm(a3);
            c = fv * c + iv * gv;
            const float h = ov * tanh_(c);

            // h history for batched FC (off the serial path; read at chunk end)
            hst[tt][lane] = (f16)h;

            // ---- register allgather of h for next step ----
            const int hp_ = DPP(__float_as_int(h), 0xB1);     // partner l^1
            const unsigned P = pack2(h, __int_as_float(hp_));
            Wr[0]  = P;
            Wr[16] = (unsigned)__shfl_xor((int)P, 32);                     // ^32
            Wr[8]  = (unsigned)__builtin_amdgcn_ds_swizzle((int)Wr[0],  0x401F); // ^16
            Wr[24] = (unsigned)__builtin_amdgcn_ds_swizzle((int)Wr[16], 0x401F);
            #pragma unroll
            for (int i = 0; i < 32; i += 8)
                Wr[i + 4] = (unsigned)DPP((int)Wr[i], 0x140);  // ^15 (mirror)
            #pragma unroll
            for (int i = 0; i < 32; i += 4)
                Wr[i + 2] = (unsigned)DPP((int)Wr[i], 0x141);  // ^7 (half-mirror)
            #pragma unroll
            for (int i = 0; i < 32; i += 2)
                Wr[i + 1] = (unsigned)DPP((int)Wr[i], 0x4E);   // ^2 (quad)

            // rotate xp pipeline
            xvA = xvB; xvB = xvC; xvC = xvN;
        }

        // ---- chunk-end batched FC (off the serial path, coalesced) ----
        const float* w0 = W_fc + 0 * FCW + (size_t)T0 * HH + lane;
        const float* w1 = W_fc + 1 * FCW + (size_t)T0 * HH + lane;
        const float* w2 = W_fc + 2 * FCW + (size_t)T0 * HH + lane;
        const float* w3 = W_fc + 3 * FCW + (size_t)T0 * HH + lane;
        for (int tt = 0; tt < TCF; ++tt) {
            const float hv = (float)hst[tt][lane];
            fc0 += hv * w0[(size_t)tt * HH];
            fc1 += hv * w1[(size_t)tt * HH];
            fc2 += hv * w2[(size_t)tt * HH];
            fc3 += hv * w3[(size_t)tt * HH];
        }
    }

    // FC reduce over hid (wave shuffle) + softmax
    #pragma unroll
    for (int off = 32; off; off >>= 1) {
        fc0 += __shfl_down(fc0, off);
        fc1 += __shfl_down(fc1, off);
        fc2 += __shfl_down(fc2, off);
        fc3 += __shfl_down(fc3, off);
    }
    if (lane == 0) {
        const float l0 = fc0 + b_fc[0], l1 = fc1 + b_fc[1];
        const float l2 = fc2 + b_fc[2], l3 = fc3 + b_fc[3];
        const float m  = fmaxf(fmaxf(l0, l1), fmaxf(l2, l3));
        const float e0 = __expf(l0 - m), e1 = __expf(l1 - m);
        const float e2 = __expf(l2 - m), e3 = __expf(l3 - m);
        const float is = __builtin_amdgcn_rcpf(e0 + e1 + e2 + e3);
        float4 o; o.x = e0 * is; o.y = e1 * is; o.z = e2 * is; o.w = e3 * is;
        *(float4*)(out + r * NCLS) = o;
    }
}

// ---------------------------------------------------------------------------
// Fallback: self-contained single kernel (R4 structure), used only if the
// workspace can't hold xp (262 MB).
// ---------------------------------------------------------------------------
#define TC   250
#define NCHUNK (TT / TC)
#define XROW 12

__global__ __attribute__((amdgpu_waves_per_eu(1, 1)))
__launch_bounds__(64) void lstm_fb(
    const float* __restrict__ x, const float* __restrict__ W_ih,
    const float* __restrict__ W_hh, const float* __restrict__ b_ih,
    const float* __restrict__ b_hh, const float* __restrict__ W_fc,
    const float* __restrict__ b_fc, float* __restrict__ out)
{
    __shared__ __align__(16) h2  xs[TC][XROW];
    __shared__ __align__(16) f16 hbuf[HH];

    const int lane = threadIdx.x;
    const int r    = blockIdx.x;

    unsigned whh[4][32];
    unsigned wih[4][11];
    float bias[4];
    #pragma unroll
    for (int g = 0; g < 4; ++g) {
        const int row = g * HH + lane;
        const float* wr = W_hh + row * HH;
        #pragma unroll
        for (int k = 0; k < 32; ++k)
            whh[g][k] = h2u(h2{(f16)wr[2 * k], (f16)wr[2 * k + 1]});
        const float* wi = W_ih + row * CC;
        #pragma unroll
        for (int k = 0; k < 11; ++k)
            wih[g][k] = h2u(h2{(f16)wi[2 * k], (f16)wi[2 * k + 1]});
        bias[g] = b_ih[row] + b_hh[row];
    }
    #pragma unroll
    for (int g = 0; g < 4; ++g) {
        #pragma unroll
        for (int k = 0; k < 32; ++k) asm volatile("" : "+v"(whh[g][k]));
        #pragma unroll
        for (int k = 0; k < 11; ++k) asm volatile("" : "+v"(wih[g][k]));
        asm volatile("" : "+v"(bias[g]));
    }

    hbuf[lane] = (f16)0.0f;
    float c = 0.0f;
    float fc0 = 0.f, fc1 = 0.f, fc2 = 0.f, fc3 = 0.f;
    const float* p0 = W_fc + 0 * FCW + lane;
    const float* p1 = W_fc + 1 * FCW + lane;
    const float* p2 = W_fc + 2 * FCW + lane;
    const float* p3 = W_fc + 3 * FCW + lane;
    const float* xrow = x + (size_t)r * (CC * TT);

    for (int chunk = 0; chunk < NCHUNK; ++chunk) {
        for (int tb = 0; tb < TC; tb += 64) {
            const int t = tb + lane;
            if (t < TC) {
                const float* gx = xrow + chunk * TC + t;
                union { h2 h[XROW]; uint4 q[3]; } U;
                #pragma unroll
                for (int k = 0; k < 11; ++k)
                    U.h[k] = h2{(f16)gx[(2 * k) * TT], (f16)gx[(2 * k + 1) * TT]};
                U.h[11] = h2{(f16)0.0f, (f16)0.0f};
                uint4* dst = (uint4*)&xs[t][0];
                dst[0] = U.q[0]; dst[1] = U.q[1]; dst[2] = U.q[2];
            }
        }
        for (int tt = 0; tt < TC; ++tt) {
            union { uint4 q[8]; h2 h[32]; } H;
            const uint4* hr = (const uint4*)hbuf;
            #pragma unroll
            for (int i = 0; i < 8; ++i) H.q[i] = hr[i];
            union { uint4 q[3]; h2 h[XROW]; } X;
            const uint4* xr = (const uint4*)&xs[tt][0];
            X.q[0] = xr[0]; X.q[1] = xr[1]; X.q[2] = xr[2];
            float w0 = *p0, w1 = *p1, w2 = *p2, w3 = *p3;
            p0 += HH; p1 += HH; p2 += HH; p3 += HH;
            float a0 = bias[0], a1 = bias[1], a2 = bias[2], a3 = bias[3];
            #pragma unroll
            for (int k = 0; k < 11; ++k) {
                a0 = __builtin_amdgcn_fdot2(X.h[k], u2h(wih[0][k]), a0, false);
                a1 = __builtin_amdgcn_fdot2(X.h[k], u2h(wih[1][k]), a1, false);
                a2 = __builtin_amdgcn_fdot2(X.h[k], u2h(wih[2][k]), a2, false);
                a3 = __builtin_amdgcn_fdot2(X.h[k], u2h(wih[3][k]), a3, false);
            }
            #pragma unroll
            for (int k = 0; k < 32; ++k) {
                a0 = __builtin_amdgcn_fdot2(H.h[k], u2h(whh[0][k]), a0, false);
                a1 = __builtin_amdgcn_fdot2(H.h[k], u2h(whh[1][k]), a1, false);
                a2 = __builtin_amdgcn_fdot2(H.h[k], u2h(whh[2][k]), a2, false);
                a3 = __builtin_amdgcn_fdot2(H.h[k], u2h(whh[3][k]), a3, false);
            }
            const float iv = sigm(a0), fv = sigm(a1);
            const float gv = tanh_(a2), ov = sigm(a3);
            c = fv * c + iv * gv;
            const float h = ov * tanh_(c);
            fc0 += h * w0; fc1 += h * w1; fc2 += h * w2; fc3 += h * w3;
            hbuf[lane] = (f16)h;
        }
    }
    #pragma unroll
    for (int off = 32; off; off >>= 1) {
        fc0 += __shfl_down(fc0, off);
        fc1 += __shfl_down(fc1, off);
        fc2 += __shfl_down(fc2, off);
        fc3 += __shfl_down(fc3, off);
    }
    if (lane == 0) {
        const float l0 = fc0 + b_fc[0], l1 = fc1 + b_fc[1];
        const float l2 = fc2 + b_fc[2], l3 = fc3 + b_fc[3];
        const float m  = fmaxf(fmaxf(l0, l1), fmaxf(l2, l3));
        const float e0 = __expf(l0 - m), e1 = __expf(l1 - m);
        const float e2 = __expf(l2 - m), e3 = __expf(l3 - m);
        const float is = __builtin_amdgcn_rcpf(e0 + e1 + e2 + e3);
        float4 o; o.x = e0 * is; o.y = e1 * is; o.z = e2 * is; o.w = e3 * is;
        *(float4*)(out + r * NCLS) = o;
    }
}

extern "C" void kernel_launch(void* const* d_in, const int* in_sizes, int n_in,
                              void* d_out, int out_size, void* d_ws, size_t ws_size,
                              hipStream_t stream) {
    const float* x    = (const float*)d_in[0];
    const float* W_ih = (const float*)d_in[1];
    const float* W_hh = (const float*)d_in[2];
    const float* b_ih = (const float*)d_in[3];
    const float* b_hh = (const float*)d_in[4];
    const float* W_fc = (const float*)d_in[5];
    const float* b_fc = (const float*)d_in[6];
    float* out = (float*)d_out;

    const size_t need = (size_t)BB * TT * HH * 4 * sizeof(f16);   // 262.1 MB
    if (d_ws != nullptr && ws_size >= need) {
        uint2* xp = (uint2*)d_ws;
        xproj<<<dim3(TT / TBX, BB), 256, 0, stream>>>(x, W_ih, b_ih, b_hh, xp);
        lstm_rec<<<BB, 64, 0, stream>>>(xp, W_hh, W_fc, b_fc, out);
    } else {
        lstm_fb<<<BB, 64, 0, stream>>>(x, W_ih, W_hh, b_ih, b_hh, W_fc, b_fc, out);
    }
}